// Round 3
// baseline (340.546 us; speedup 1.0000x reference)
//
#include <hip/hip_runtime.h>
#include <hip/hip_bf16.h>
#include <stdint.h>

typedef float f32x4 __attribute__((ext_vector_type(4)));
typedef short s16x8 __attribute__((ext_vector_type(8)));
typedef unsigned short u16;

__device__ __forceinline__ u16 f2bf(float f) {
  uint32_t u = __float_as_uint(f);
  u = (u + 0x7fffu + ((u >> 16) & 1u)) >> 16;
  return (u16)u;
}

// ---------------- K0a: BN fold params
__global__ void k_params(const float* __restrict__ gamma, const float* __restrict__ beta,
                         const float* __restrict__ mean, const float* __restrict__ var,
                         float* __restrict__ bnS, float* __restrict__ bnT) {
  int i = threadIdx.x;
  if (i < 512) {
    float s = gamma[i] * rsqrtf(var[i] + 1e-5f);
    bnS[i] = s;
    bnT[i] = beta[i] - mean[i] * s;
  }
}

// ---------------- K0b: f32 -> bf16 convert
__global__ void k_convert(const float* __restrict__ in, u16* __restrict__ out, int n4) {
  int i = blockIdx.x * blockDim.x + threadIdx.x;
  if (i < n4) {
    float4 v = ((const float4*)in)[i];
    ushort4 o;
    o.x = f2bf(v.x); o.y = f2bf(v.y); o.z = f2bf(v.z); o.w = f2bf(v.w);
    ((ushort4*)out)[i] = o;
  }
}

// ---------------- K0c: border2
__global__ void k_border2(const float* __restrict__ w2, const float* __restrict__ b2,
                          const float* __restrict__ bnT, float* __restrict__ border2) {
  int o = blockIdx.x;
  int l = threadIdx.x;
  float s = 0.f;
  for (int j = 0; j < 8; ++j) {
    int c = l + 64 * j;
    s += w2[o * 512 + c] * fmaxf(bnT[c], 0.f);
  }
  for (int off = 32; off > 0; off >>= 1) s += __shfl_down(s, off, 64);
  if (l == 0) border2[o] = s + b2[o];
}

// ---------------- K1 (fused): GEMM1 + transpose/convert of A, dbuf LDS, 2-deep prefetch.
// Tile 128m x 64n, 4 waves (wave w: rows w*32..+31, all 64 n). grid = 128mt x 8nt = 1024.
__global__ __launch_bounds__(256, 3) void k_gemm1(
    const float* __restrict__ X, const u16* __restrict__ Bw,
    const float* __restrict__ bnS, const float* __restrict__ bnT,
    u16* __restrict__ H) {
  const int K = 5632;
  const int NT = 176;                           // K/32
  __shared__ __align__(16) u16 sA[2][128 * 40]; // pad-40 rows: bank-clean r/w
  __shared__ __align__(16) u16 sB[2][64 * 32];  // granule-swizzled
  int nb = gridDim.x;                           // 1024
  int id = blockIdx.x;
  int li = (id & 7) * (nb >> 3) + (id >> 3);    // XCD swizzle: 8 nt of an mt on one XCD
  int nt = li & 7;
  int mt = li >> 3;
  int t = threadIdx.x;
  int l = t & 63, w = t >> 6;

  // B staging: 1 x s16x8 per thread
  const u16* gB = Bw + (size_t)(nt * 64 + (t >> 2)) * K + (t & 3) * 8;
  int woB;
  { int n = t >> 2, g = t & 3; woB = (n * 4 + (g ^ ((n >> 1) & 3))) * 8; }

  // A staging: 2 rows x 8 consecutive k per lane (float2 x 8 at 4KB stride)
  int m0 = (w >> 1) * 64 + 2 * (l & 31);
  int kh = w & 1, kq = l >> 5;
  int bidx = mt >> 3, p0 = (mt & 7) * 128;
  const float* gA = X + (size_t)bidx * (5632ull * 1024) + (size_t)(kh * 16 + kq * 8) * 1024
                      + p0 + m0;
  int aoff = m0 * 40 + kh * 16 + kq * 8;

  int offA[2], offB[4];
#pragma unroll
  for (int f = 0; f < 2; ++f) offA[f] = (w * 32 + f * 16 + (l & 15)) * 40 + (l >> 4) * 8;
#pragma unroll
  for (int f = 0; f < 4; ++f) {
    int n = f * 16 + (l & 15), g = l >> 4;
    offB[f] = (n * 4 + (g ^ ((n >> 1) & 3))) * 8;
  }

  f32x4 acc[2][4] = {};

  auto loadA = [&](float2* va) {
#pragma unroll
    for (int ii = 0; ii < 8; ++ii) va[ii] = *(const float2*)(gA + (size_t)ii * 1024);
  };
  auto stage = [&](const float2* va, s16x8 rB, u16* bA, u16* bB) {
    union { u16 u[16]; s16x8 v[2]; } cv;
#pragma unroll
    for (int ii = 0; ii < 8; ++ii) {
      cv.u[ii] = f2bf(va[ii].x);
      cv.u[8 + ii] = f2bf(va[ii].y);
    }
    *(s16x8*)(bA + aoff) = cv.v[0];
    *(s16x8*)(bA + aoff + 40) = cv.v[1];
    *(s16x8*)(bB + woB) = rB;
  };
  auto compute = [&](const u16* bA, const u16* bB) {
    s16x8 af[2], bfr[4];
#pragma unroll
    for (int f = 0; f < 2; ++f) af[f] = *(const s16x8*)(bA + offA[f]);
#pragma unroll
    for (int f = 0; f < 4; ++f) bfr[f] = *(const s16x8*)(bB + offB[f]);
#pragma unroll
    for (int ii = 0; ii < 2; ++ii)
#pragma unroll
      for (int j = 0; j < 4; ++j)
        acc[ii][j] = __builtin_amdgcn_mfma_f32_16x16x32_bf16(af[ii], bfr[j], acc[ii][j], 0, 0, 0);
  };

  float2 vaA[8], vaB[8];
  s16x8 rBa, rBb;

  // prologue: tile0 -> buf0; tile1 -> regs
  loadA(vaA); rBa = *(const s16x8*)gB;
  stage(vaA, rBa, sA[0], sB[0]);
  gA += 32 * 1024; gB += 32;
  loadA(vaB); rBb = *(const s16x8*)gB;

  for (int i = 0; i < NT; i += 2) {
    // -- sub-iter i: compute buf0(tile i); issue tile i+2 -> setA; stage tile i+1 -> buf1
    __syncthreads();
    if (i + 2 < NT) {
      gA += 32 * 1024; gB += 32;
      loadA(vaA); rBa = *(const s16x8*)gB;
    }
    compute(sA[0], sB[0]);
    stage(vaB, rBb, sA[1], sB[1]);
    // -- sub-iter i+1: compute buf1(tile i+1); issue tile i+3 -> setB; stage tile i+2 -> buf0
    __syncthreads();
    if (i + 3 < NT) {
      gA += 32 * 1024; gB += 32;
      loadA(vaB); rBb = *(const s16x8*)gB;
    }
    compute(sA[1], sB[1]);
    if (i + 2 < NT) stage(vaA, rBa, sA[0], sB[0]);
  }

  int mb = mt * 128 + w * 32;
  int nb0 = nt * 64;
#pragma unroll
  for (int j = 0; j < 4; ++j) {
    int n_g = nb0 + j * 16 + (l & 15);
    float s = bnS[n_g], tt = bnT[n_g];
#pragma unroll
    for (int i = 0; i < 2; ++i)
#pragma unroll
      for (int r = 0; r < 4; ++r) {
        int m_g = mb + i * 16 + (l >> 4) * 4 + r;
        float v = fmaxf(acc[i][j][r] * s + tt, 0.f);
        H[(size_t)m_g * 512 + n_g] = f2bf(v);
      }
  }
}

// ---------------- GEMM2: 128x128 tile, BK=32, 4 waves; epilogue acc + b2 -> f32
__global__ __launch_bounds__(256, 2) void k_gemm2(
    const u16* __restrict__ A, const u16* __restrict__ B,
    const float* __restrict__ b2, float* __restrict__ C) {
  const int K = 512;
  __shared__ __align__(16) u16 sA[4096];
  __shared__ __align__(16) u16 sB[4096];
  int nb = gridDim.x;
  int id = blockIdx.x;
  int li = (id & 7) * (nb >> 3) + (id >> 3);
  int nt = li % 3;
  int mt = li / 3;
  int t = threadIdx.x;
  int l = t & 63, w = t >> 6;
  int wm = w >> 1, wn = w & 1;

  auto swz = [](int u) { int m = u >> 2, g = u & 3; return (m * 4 + (g ^ ((m >> 1) & 3))) * 8; };
  int wo0 = swz(t), wo1 = swz(t + 256);

  const u16* gA0 = A + (size_t)(mt * 128 + (t >> 2)) * K + (t & 3) * 8;
  const u16* gA1 = gA0 + (size_t)64 * K;
  const u16* gB0 = B + (size_t)(nt * 128 + (t >> 2)) * K + (t & 3) * 8;
  const u16* gB1 = gB0 + (size_t)64 * K;

  int offA[4], offB[4];
#pragma unroll
  for (int f = 0; f < 4; ++f) {
    int g = l >> 4;
    int m = wm * 64 + f * 16 + (l & 15);
    offA[f] = (m * 4 + (g ^ ((m >> 1) & 3))) * 8;
    int n = wn * 64 + f * 16 + (l & 15);
    offB[f] = (n * 4 + (g ^ ((n >> 1) & 3))) * 8;
  }

  f32x4 acc[4][4] = {};

  s16x8 rA0 = *(const s16x8*)gA0;
  s16x8 rA1 = *(const s16x8*)gA1;
  s16x8 rB0 = *(const s16x8*)gB0;
  s16x8 rB1 = *(const s16x8*)gB1;

  for (int k0 = 0; k0 < K; k0 += 32) {
    *(s16x8*)(sA + wo0) = rA0;
    *(s16x8*)(sA + wo1) = rA1;
    *(s16x8*)(sB + wo0) = rB0;
    *(s16x8*)(sB + wo1) = rB1;
    __syncthreads();
    if (k0 + 32 < K) {
      gA0 += 32; gA1 += 32; gB0 += 32; gB1 += 32;
      rA0 = *(const s16x8*)gA0;
      rA1 = *(const s16x8*)gA1;
      rB0 = *(const s16x8*)gB0;
      rB1 = *(const s16x8*)gB1;
    }
    s16x8 af[4], bf[4];
#pragma unroll
    for (int f = 0; f < 4; ++f) {
      af[f] = *(const s16x8*)(sA + offA[f]);
      bf[f] = *(const s16x8*)(sB + offB[f]);
    }
#pragma unroll
    for (int i = 0; i < 4; ++i)
#pragma unroll
      for (int j = 0; j < 4; ++j)
        acc[i][j] = __builtin_amdgcn_mfma_f32_16x16x32_bf16(af[i], bf[j], acc[i][j], 0, 0, 0);
    __syncthreads();
  }

  int mb = mt * 128 + wm * 64;
  int nbase = nt * 128 + wn * 64;
#pragma unroll
  for (int j = 0; j < 4; ++j) {
    int n_g = nbase + j * 16 + (l & 15);
    float bias = b2[n_g];
#pragma unroll
    for (int i = 0; i < 4; ++i)
#pragma unroll
      for (int r = 0; r < 4; ++r) {
        int m_g = mb + i * 16 + (l >> 4) * 4 + r;
        C[(size_t)m_g * 384 + n_g] = acc[i][j][r] + bias;
      }
  }
}

// ---------------- K4: fused DUC + softmax + bilinear(304->256, align_corners)
__global__ __launch_bounds__(256) void k_out(const float* __restrict__ c2,
                                             const float* __restrict__ border2,
                                             float* __restrict__ out) {
  int b = blockIdx.x >> 8;
  int oy = blockIdx.x & 255;
  int ox = threadIdx.x;
  const float SCL = 303.0f / 255.0f;
  float ys = oy * SCL, xs = ox * SCL;
  int y0 = (int)ys; if (y0 > 303) y0 = 303;
  int x0 = (int)xs; if (x0 > 303) x0 = 303;
  float wy = ys - (float)y0, wx = xs - (float)x0;
  int y1 = y0 + 1; if (y1 > 303) y1 = 303;
  int x1 = x0 + 1; if (x1 > 303) x1 = 303;
  int syA[2] = {y0, y1};
  int sxA[2] = {x0, x1};
  float wyA[2] = {1.f - wy, wy};
  float wxA[2] = {1.f - wx, wx};
  float acc[6] = {0.f, 0.f, 0.f, 0.f, 0.f, 0.f};
#pragma unroll
  for (int cy = 0; cy < 2; ++cy) {
#pragma unroll
    for (int cx = 0; cx < 2; ++cx) {
      float wgt = wyA[cy] * wxA[cx];
      int sy = syA[cy], sx = sxA[cx];
      if (sy >= 256 || sx >= 256) {
        float p = wgt * (1.f / 6.f);
#pragma unroll
        for (int c = 0; c < 6; ++c) acc[c] += p;
      } else {
        int i = sy >> 3, j = sx >> 3;
        int sub = ((sy & 7) << 3) | (sx & 7);
        const float* src;
        if (i == 0 || j == 0)
          src = border2 + sub;
        else
          src = c2 + (size_t)((b << 10) + ((i - 1) << 5) + (j - 1)) * 384 + sub;
        float l0 = src[0],   l1 = src[64],  l2 = src[128];
        float l3 = src[192], l4 = src[256], l5 = src[320];
        float mx = fmaxf(fmaxf(fmaxf(l0, l1), fmaxf(l2, l3)), fmaxf(l4, l5));
        float e0 = __expf(l0 - mx), e1 = __expf(l1 - mx), e2 = __expf(l2 - mx);
        float e3 = __expf(l3 - mx), e4 = __expf(l4 - mx), e5 = __expf(l5 - mx);
        float ssum = e0 + e1 + e2 + e3 + e4 + e5;
        float r = wgt / ssum;
        acc[0] += e0 * r; acc[1] += e1 * r; acc[2] += e2 * r;
        acc[3] += e3 * r; acc[4] += e4 * r; acc[5] += e5 * r;
      }
    }
  }
  size_t base = ((size_t)b * 6) << 16;
  int pix = (oy << 8) | ox;
#pragma unroll
  for (int c = 0; c < 6; ++c) out[base + ((size_t)c << 16) + pix] = acc[c];
}

extern "C" void kernel_launch(void* const* d_in, const int* in_sizes, int n_in,
                              void* d_out, int out_size, void* d_ws, size_t ws_size,
                              hipStream_t stream) {
  const float* x     = (const float*)d_in[0];
  const float* w1    = (const float*)d_in[1];
  const float* gamma = (const float*)d_in[2];
  const float* beta  = (const float*)d_in[3];
  const float* mean  = (const float*)d_in[4];
  const float* var   = (const float*)d_in[5];
  const float* w2    = (const float*)d_in[6];
  const float* b2    = (const float*)d_in[7];
  float* out = (float*)d_out;

  char* ws = (char*)d_ws;
  size_t off = 0;
  auto alloc = [&](size_t bytes) -> char* {
    char* p = ws + off;
    off = (off + bytes + 255) & ~(size_t)255;
    return p;
  };
  u16*   w1bf    = (u16*)alloc(512ull * 5632 * 2);
  u16*   w2bf    = (u16*)alloc(384ull * 512 * 2);
  float* bnS     = (float*)alloc(512 * 4);
  float* bnT     = (float*)alloc(512 * 4);
  float* border2 = (float*)alloc(384 * 4);
  u16*   h       = (u16*)alloc(16384ull * 512 * 2);
  float* c2      = (float*)alloc(16384ull * 384 * 4);
  (void)ws_size;

  k_params<<<dim3(1), dim3(512), 0, stream>>>(gamma, beta, mean, var, bnS, bnT);
  k_convert<<<dim3(2816), dim3(256), 0, stream>>>(w1, w1bf, 512 * 5632 / 4);
  k_convert<<<dim3(192), dim3(256), 0, stream>>>(w2, w2bf, 384 * 512 / 4);
  k_border2<<<dim3(384), dim3(64), 0, stream>>>(w2, b2, bnT, border2);

  k_gemm1<<<dim3(1024), dim3(256), 0, stream>>>(x, w1bf, bnS, bnT, h);
  k_gemm2<<<dim3(128 * 3), dim3(256), 0, stream>>>(h, w2bf, b2, c2);
  k_out<<<dim3(16 * 256), dim3(256), 0, stream>>>(c2, border2, out);
}

// Round 4
// 265.158 us; speedup vs baseline: 1.2843x; 1.2843x over previous
//
#include <hip/hip_runtime.h>
#include <hip/hip_bf16.h>
#include <stdint.h>

typedef float f32x4 __attribute__((ext_vector_type(4)));
typedef short s16x8 __attribute__((ext_vector_type(8)));
typedef unsigned short u16;

__device__ __forceinline__ u16 f2bf(float f) {
  uint32_t u = __float_as_uint(f);
  u = (u + 0x7fffu + ((u >> 16) & 1u)) >> 16;
  return (u16)u;
}

// Hot-path convert: compiler lowers __float2bfloat16 to HW v_cvt_pk_bf16_f32 (RNE)
__device__ __forceinline__ u16 cvt_bf(float f) {
  union { __hip_bfloat16 h; u16 u; } c;
  c.h = __float2bfloat16(f);
  return c.u;
}

// ---------------- K0a: BN fold params
__global__ void k_params(const float* __restrict__ gamma, const float* __restrict__ beta,
                         const float* __restrict__ mean, const float* __restrict__ var,
                         float* __restrict__ bnS, float* __restrict__ bnT) {
  int i = threadIdx.x;
  if (i < 512) {
    float s = gamma[i] * rsqrtf(var[i] + 1e-5f);
    bnS[i] = s;
    bnT[i] = beta[i] - mean[i] * s;
  }
}

// ---------------- K0b: f32 -> bf16 convert
__global__ void k_convert(const float* __restrict__ in, u16* __restrict__ out, int n4) {
  int i = blockIdx.x * blockDim.x + threadIdx.x;
  if (i < n4) {
    float4 v = ((const float4*)in)[i];
    ushort4 o;
    o.x = f2bf(v.x); o.y = f2bf(v.y); o.z = f2bf(v.z); o.w = f2bf(v.w);
    ((ushort4*)out)[i] = o;
  }
}

// ---------------- K0c: border2
__global__ void k_border2(const float* __restrict__ w2, const float* __restrict__ b2,
                          const float* __restrict__ bnT, float* __restrict__ border2) {
  int o = blockIdx.x;
  int l = threadIdx.x;
  float s = 0.f;
  for (int j = 0; j < 8; ++j) {
    int c = l + 64 * j;
    s += w2[o * 512 + c] * fmaxf(bnT[c], 0.f);
  }
  for (int off = 32; off > 0; off >>= 1) s += __shfl_down(s, off, 64);
  if (l == 0) border2[o] = s + b2[o];
}

// ---------------- K1 (fused): GEMM1 + in-kernel transpose/convert of A.
// 128m x 128n tile, 4 waves (wm,wn in 2x2, each 64m x 64n). grid = 128mt x 4nt = 512.
// Double-buffered LDS + 2-deep register prefetch; A converted via HW cvt_pk.
__global__ __launch_bounds__(256, 2) void k_gemm1(
    const float* __restrict__ X, const u16* __restrict__ Bw,
    const float* __restrict__ bnS, const float* __restrict__ bnT,
    u16* __restrict__ H) {
  const int K = 5632;
  const int NT = 176;                            // K/32
  __shared__ __align__(16) u16 sA[2][128 * 40];  // pad-40 rows: bank-clean
  __shared__ __align__(16) u16 sB[2][4096];      // granule-swizzled
  int nb = gridDim.x;                            // 512
  int id = blockIdx.x;
  int li = (id & 7) * (nb >> 3) + (id >> 3);     // XCD swizzle
  int nt = li & 3;
  int mt = li >> 2;
  int t = threadIdx.x;
  int l = t & 63, w = t >> 6;
  int wm = w >> 1, wn = w & 1;

  // B staging: 2 x s16x8 per thread, granule swizzle
  auto swz = [](int u) { int m = u >> 2, g = u & 3; return (m * 4 + (g ^ ((m >> 1) & 3))) * 8; };
  int wo0 = swz(t), wo1 = swz(t + 256);
  const u16* gB0 = Bw + (size_t)(nt * 128 + (t >> 2)) * K + (t & 3) * 8;
  const u16* gB1 = gB0 + (size_t)64 * K;

  // A staging: 2 rows x 8 consecutive k per lane (float2 x 8 at 4KB stride)
  int m0 = (w >> 1) * 64 + 2 * (l & 31);
  int kh = w & 1, kq = l >> 5;
  int bidx = mt >> 3, p0 = (mt & 7) * 128;
  const float* gA = X + (size_t)bidx * (5632ull * 1024) + (size_t)(kh * 16 + kq * 8) * 1024
                      + p0 + m0;
  int aoff = m0 * 40 + kh * 16 + kq * 8;

  int offA[4], offB[4];
#pragma unroll
  for (int f = 0; f < 4; ++f) {
    int m = wm * 64 + f * 16 + (l & 15);
    offA[f] = m * 40 + (l >> 4) * 8;
    int n = wn * 64 + f * 16 + (l & 15);
    int g = l >> 4;
    offB[f] = (n * 4 + (g ^ ((n >> 1) & 3))) * 8;
  }

  f32x4 acc[4][4] = {};

  auto loadA = [&](float2* va) {
#pragma unroll
    for (int ii = 0; ii < 8; ++ii) va[ii] = *(const float2*)(gA + (size_t)ii * 1024);
  };
  auto stage = [&](const float2* va, s16x8 r0, s16x8 r1, u16* bA, u16* bB) {
    union { u16 u[16]; s16x8 v[2]; } cv;
#pragma unroll
    for (int ii = 0; ii < 8; ++ii) {
      cv.u[ii] = cvt_bf(va[ii].x);
      cv.u[8 + ii] = cvt_bf(va[ii].y);
    }
    *(s16x8*)(bA + aoff) = cv.v[0];
    *(s16x8*)(bA + aoff + 40) = cv.v[1];
    *(s16x8*)(bB + wo0) = r0;
    *(s16x8*)(bB + wo1) = r1;
  };
  auto compute = [&](const u16* bA, const u16* bB) {
    s16x8 af[4], bfr[4];
#pragma unroll
    for (int f = 0; f < 4; ++f) {
      af[f] = *(const s16x8*)(bA + offA[f]);
      bfr[f] = *(const s16x8*)(bB + offB[f]);
    }
#pragma unroll
    for (int ii = 0; ii < 4; ++ii)
#pragma unroll
      for (int j = 0; j < 4; ++j)
        acc[ii][j] = __builtin_amdgcn_mfma_f32_16x16x32_bf16(af[ii], bfr[j], acc[ii][j], 0, 0, 0);
  };

  float2 vaA[8], vaB[8];
  s16x8 rBa0, rBa1, rBb0, rBb1;

  // prologue: tile0 -> buf0; tile1 -> regs
  loadA(vaA); rBa0 = *(const s16x8*)gB0; rBa1 = *(const s16x8*)gB1;
  stage(vaA, rBa0, rBa1, sA[0], sB[0]);
  gA += 32 * 1024; gB0 += 32; gB1 += 32;
  loadA(vaB); rBb0 = *(const s16x8*)gB0; rBb1 = *(const s16x8*)gB1;

  for (int i = 0; i < NT; i += 2) {
    // sub-iter i: compute buf0(tile i); issue tile i+2 -> setA; stage tile i+1 -> buf1
    __syncthreads();
    if (i + 2 < NT) {
      gA += 32 * 1024; gB0 += 32; gB1 += 32;
      loadA(vaA); rBa0 = *(const s16x8*)gB0; rBa1 = *(const s16x8*)gB1;
    }
    compute(sA[0], sB[0]);
    stage(vaB, rBb0, rBb1, sA[1], sB[1]);
    // sub-iter i+1: compute buf1(tile i+1); issue tile i+3 -> setB; stage tile i+2 -> buf0
    __syncthreads();
    if (i + 3 < NT) {
      gA += 32 * 1024; gB0 += 32; gB1 += 32;
      loadA(vaB); rBb0 = *(const s16x8*)gB0; rBb1 = *(const s16x8*)gB1;
    }
    compute(sA[1], sB[1]);
    if (i + 2 < NT) stage(vaA, rBa0, rBa1, sA[0], sB[0]);
  }

  int mb = mt * 128 + wm * 64;
  int nbase = nt * 128 + wn * 64;
#pragma unroll
  for (int j = 0; j < 4; ++j) {
    int n_g = nbase + j * 16 + (l & 15);
    float s = bnS[n_g], tt = bnT[n_g];
#pragma unroll
    for (int i = 0; i < 4; ++i)
#pragma unroll
      for (int r = 0; r < 4; ++r) {
        int m_g = mb + i * 16 + (l >> 4) * 4 + r;
        float v = fmaxf(acc[i][j][r] * s + tt, 0.f);
        H[(size_t)m_g * 512 + n_g] = f2bf(v);
      }
  }
}

// ---------------- GEMM2: 128x128 tile, BK=32, 4 waves; epilogue acc + b2 -> f32
__global__ __launch_bounds__(256, 2) void k_gemm2(
    const u16* __restrict__ A, const u16* __restrict__ B,
    const float* __restrict__ b2, float* __restrict__ C) {
  const int K = 512;
  __shared__ __align__(16) u16 sA[4096];
  __shared__ __align__(16) u16 sB[4096];
  int nb = gridDim.x;
  int id = blockIdx.x;
  int li = (id & 7) * (nb >> 3) + (id >> 3);
  int nt = li % 3;
  int mt = li / 3;
  int t = threadIdx.x;
  int l = t & 63, w = t >> 6;
  int wm = w >> 1, wn = w & 1;

  auto swz = [](int u) { int m = u >> 2, g = u & 3; return (m * 4 + (g ^ ((m >> 1) & 3))) * 8; };
  int wo0 = swz(t), wo1 = swz(t + 256);

  const u16* gA0 = A + (size_t)(mt * 128 + (t >> 2)) * K + (t & 3) * 8;
  const u16* gA1 = gA0 + (size_t)64 * K;
  const u16* gB0 = B + (size_t)(nt * 128 + (t >> 2)) * K + (t & 3) * 8;
  const u16* gB1 = gB0 + (size_t)64 * K;

  int offA[4], offB[4];
#pragma unroll
  for (int f = 0; f < 4; ++f) {
    int g = l >> 4;
    int m = wm * 64 + f * 16 + (l & 15);
    offA[f] = (m * 4 + (g ^ ((m >> 1) & 3))) * 8;
    int n = wn * 64 + f * 16 + (l & 15);
    offB[f] = (n * 4 + (g ^ ((n >> 1) & 3))) * 8;
  }

  f32x4 acc[4][4] = {};

  s16x8 rA0 = *(const s16x8*)gA0;
  s16x8 rA1 = *(const s16x8*)gA1;
  s16x8 rB0 = *(const s16x8*)gB0;
  s16x8 rB1 = *(const s16x8*)gB1;

  for (int k0 = 0; k0 < K; k0 += 32) {
    *(s16x8*)(sA + wo0) = rA0;
    *(s16x8*)(sA + wo1) = rA1;
    *(s16x8*)(sB + wo0) = rB0;
    *(s16x8*)(sB + wo1) = rB1;
    __syncthreads();
    if (k0 + 32 < K) {
      gA0 += 32; gA1 += 32; gB0 += 32; gB1 += 32;
      rA0 = *(const s16x8*)gA0;
      rA1 = *(const s16x8*)gA1;
      rB0 = *(const s16x8*)gB0;
      rB1 = *(const s16x8*)gB1;
    }
    s16x8 af[4], bf[4];
#pragma unroll
    for (int f = 0; f < 4; ++f) {
      af[f] = *(const s16x8*)(sA + offA[f]);
      bf[f] = *(const s16x8*)(sB + offB[f]);
    }
#pragma unroll
    for (int i = 0; i < 4; ++i)
#pragma unroll
      for (int j = 0; j < 4; ++j)
        acc[i][j] = __builtin_amdgcn_mfma_f32_16x16x32_bf16(af[i], bf[j], acc[i][j], 0, 0, 0);
    __syncthreads();
  }

  int mb = mt * 128 + wm * 64;
  int nbase = nt * 128 + wn * 64;
#pragma unroll
  for (int j = 0; j < 4; ++j) {
    int n_g = nbase + j * 16 + (l & 15);
    float bias = b2[n_g];
#pragma unroll
    for (int i = 0; i < 4; ++i)
#pragma unroll
      for (int r = 0; r < 4; ++r) {
        int m_g = mb + i * 16 + (l >> 4) * 4 + r;
        C[(size_t)m_g * 384 + n_g] = acc[i][j][r] + bias;
      }
  }
}

// ---------------- K4: fused DUC + softmax + bilinear(304->256, align_corners)
__global__ __launch_bounds__(256) void k_out(const float* __restrict__ c2,
                                             const float* __restrict__ border2,
                                             float* __restrict__ out) {
  int b = blockIdx.x >> 8;
  int oy = blockIdx.x & 255;
  int ox = threadIdx.x;
  const float SCL = 303.0f / 255.0f;
  float ys = oy * SCL, xs = ox * SCL;
  int y0 = (int)ys; if (y0 > 303) y0 = 303;
  int x0 = (int)xs; if (x0 > 303) x0 = 303;
  float wy = ys - (float)y0, wx = xs - (float)x0;
  int y1 = y0 + 1; if (y1 > 303) y1 = 303;
  int x1 = x0 + 1; if (x1 > 303) x1 = 303;
  int syA[2] = {y0, y1};
  int sxA[2] = {x0, x1};
  float wyA[2] = {1.f - wy, wy};
  float wxA[2] = {1.f - wx, wx};
  float acc[6] = {0.f, 0.f, 0.f, 0.f, 0.f, 0.f};
#pragma unroll
  for (int cy = 0; cy < 2; ++cy) {
#pragma unroll
    for (int cx = 0; cx < 2; ++cx) {
      float wgt = wyA[cy] * wxA[cx];
      int sy = syA[cy], sx = sxA[cx];
      if (sy >= 256 || sx >= 256) {
        float p = wgt * (1.f / 6.f);
#pragma unroll
        for (int c = 0; c < 6; ++c) acc[c] += p;
      } else {
        int i = sy >> 3, j = sx >> 3;
        int sub = ((sy & 7) << 3) | (sx & 7);
        const float* src;
        if (i == 0 || j == 0)
          src = border2 + sub;
        else
          src = c2 + (size_t)((b << 10) + ((i - 1) << 5) + (j - 1)) * 384 + sub;
        float l0 = src[0],   l1 = src[64],  l2 = src[128];
        float l3 = src[192], l4 = src[256], l5 = src[320];
        float mx = fmaxf(fmaxf(fmaxf(l0, l1), fmaxf(l2, l3)), fmaxf(l4, l5));
        float e0 = __expf(l0 - mx), e1 = __expf(l1 - mx), e2 = __expf(l2 - mx);
        float e3 = __expf(l3 - mx), e4 = __expf(l4 - mx), e5 = __expf(l5 - mx);
        float ssum = e0 + e1 + e2 + e3 + e4 + e5;
        float r = wgt / ssum;
        acc[0] += e0 * r; acc[1] += e1 * r; acc[2] += e2 * r;
        acc[3] += e3 * r; acc[4] += e4 * r; acc[5] += e5 * r;
      }
    }
  }
  size_t base = ((size_t)b * 6) << 16;
  int pix = (oy << 8) | ox;
#pragma unroll
  for (int c = 0; c < 6; ++c) out[base + ((size_t)c << 16) + pix] = acc[c];
}

extern "C" void kernel_launch(void* const* d_in, const int* in_sizes, int n_in,
                              void* d_out, int out_size, void* d_ws, size_t ws_size,
                              hipStream_t stream) {
  const float* x     = (const float*)d_in[0];
  const float* w1    = (const float*)d_in[1];
  const float* gamma = (const float*)d_in[2];
  const float* beta  = (const float*)d_in[3];
  const float* mean  = (const float*)d_in[4];
  const float* var   = (const float*)d_in[5];
  const float* w2    = (const float*)d_in[6];
  const float* b2    = (const float*)d_in[7];
  float* out = (float*)d_out;

  char* ws = (char*)d_ws;
  size_t off = 0;
  auto alloc = [&](size_t bytes) -> char* {
    char* p = ws + off;
    off = (off + bytes + 255) & ~(size_t)255;
    return p;
  };
  u16*   w1bf    = (u16*)alloc(512ull * 5632 * 2);
  u16*   w2bf    = (u16*)alloc(384ull * 512 * 2);
  float* bnS     = (float*)alloc(512 * 4);
  float* bnT     = (float*)alloc(512 * 4);
  float* border2 = (float*)alloc(384 * 4);
  u16*   h       = (u16*)alloc(16384ull * 512 * 2);
  float* c2      = (float*)alloc(16384ull * 384 * 4);
  (void)ws_size;

  k_params<<<dim3(1), dim3(512), 0, stream>>>(gamma, beta, mean, var, bnS, bnT);
  k_convert<<<dim3(2816), dim3(256), 0, stream>>>(w1, w1bf, 512 * 5632 / 4);
  k_convert<<<dim3(192), dim3(256), 0, stream>>>(w2, w2bf, 384 * 512 / 4);
  k_border2<<<dim3(384), dim3(64), 0, stream>>>(w2, b2, bnT, border2);

  k_gemm1<<<dim3(512), dim3(256), 0, stream>>>(x, w1bf, bnS, bnT, h);
  k_gemm2<<<dim3(128 * 3), dim3(256), 0, stream>>>(h, w2bf, b2, c2);
  k_out<<<dim3(16 * 256), dim3(256), 0, stream>>>(c2, border2, out);
}

// Round 5
// 259.101 us; speedup vs baseline: 1.3143x; 1.0234x over previous
//
#include <hip/hip_runtime.h>
#include <hip/hip_bf16.h>
#include <stdint.h>

typedef float f32x4 __attribute__((ext_vector_type(4)));
typedef short s16x8 __attribute__((ext_vector_type(8)));
typedef unsigned short u16;

__device__ __forceinline__ u16 f2bf(float f) {
  uint32_t u = __float_as_uint(f);
  u = (u + 0x7fffu + ((u >> 16) & 1u)) >> 16;
  return (u16)u;
}

// Hot-path convert: compiler lowers __float2bfloat16 to HW cvt (RNE)
__device__ __forceinline__ u16 cvt_bf(float f) {
  union { __hip_bfloat16 h; u16 u; } c;
  c.h = __float2bfloat16(f);
  return c.u;
}

// Barrier that does NOT drain vmcnt: own LDS ops drained (lgkmcnt), global loads
// stay in flight across the barrier (T4 counted-vmcnt pipeline).
__device__ __forceinline__ void wg_barrier_lds() {
  __builtin_amdgcn_sched_barrier(0);
  asm volatile("s_waitcnt lgkmcnt(0)" ::: "memory");
  __builtin_amdgcn_s_barrier();
  __builtin_amdgcn_sched_barrier(0);
}

// ---------------- K0a: BN fold params
__global__ void k_params(const float* __restrict__ gamma, const float* __restrict__ beta,
                         const float* __restrict__ mean, const float* __restrict__ var,
                         float* __restrict__ bnS, float* __restrict__ bnT) {
  int i = threadIdx.x;
  if (i < 512) {
    float s = gamma[i] * rsqrtf(var[i] + 1e-5f);
    bnS[i] = s;
    bnT[i] = beta[i] - mean[i] * s;
  }
}

// ---------------- K0b: f32 -> bf16 convert
__global__ void k_convert(const float* __restrict__ in, u16* __restrict__ out, int n4) {
  int i = blockIdx.x * blockDim.x + threadIdx.x;
  if (i < n4) {
    float4 v = ((const float4*)in)[i];
    ushort4 o;
    o.x = f2bf(v.x); o.y = f2bf(v.y); o.z = f2bf(v.z); o.w = f2bf(v.w);
    ((ushort4*)out)[i] = o;
  }
}

// ---------------- K0c: border2
__global__ void k_border2(const float* __restrict__ w2, const float* __restrict__ b2,
                          const float* __restrict__ bnT, float* __restrict__ border2) {
  int o = blockIdx.x;
  int l = threadIdx.x;
  float s = 0.f;
  for (int j = 0; j < 8; ++j) {
    int c = l + 64 * j;
    s += w2[o * 512 + c] * fmaxf(bnT[c], 0.f);
  }
  for (int off = 32; off > 0; off >>= 1) s += __shfl_down(s, off, 64);
  if (l == 0) border2[o] = s + b2[o];
}

// ---------------- K1 (fused): GEMM1 + in-kernel transpose/convert of A.
// 128m x 128n tile, 4 waves. Dbuf LDS + 2-deep register prefetch; barriers do NOT
// drain vmcnt, so prefetch loads span ~2 K-steps (the round-2..4 bottleneck).
__global__ __launch_bounds__(256, 2) void k_gemm1(
    const float* __restrict__ X, const u16* __restrict__ Bw,
    const float* __restrict__ bnS, const float* __restrict__ bnT,
    u16* __restrict__ H) {
  const int K = 5632;
  const int NT = 176;                            // K/32
  __shared__ __align__(16) u16 sA[2][128 * 40];  // pad-40 rows: bank-clean
  __shared__ __align__(16) u16 sB[2][4096];      // granule-swizzled
  int nb = gridDim.x;                            // 512
  int id = blockIdx.x;
  int li = (id & 7) * (nb >> 3) + (id >> 3);     // XCD swizzle
  int nt = li & 3;
  int mt = li >> 2;
  int t = threadIdx.x;
  int l = t & 63, w = t >> 6;
  int wm = w >> 1, wn = w & 1;

  auto swz = [](int u) { int m = u >> 2, g = u & 3; return (m * 4 + (g ^ ((m >> 1) & 3))) * 8; };
  int wo0 = swz(t), wo1 = swz(t + 256);
  const u16* gB0 = Bw + (size_t)(nt * 128 + (t >> 2)) * K + (t & 3) * 8;
  const u16* gB1 = gB0 + (size_t)64 * K;

  int m0 = (w >> 1) * 64 + 2 * (l & 31);
  int kh = w & 1, kq = l >> 5;
  int bidx = mt >> 3, p0 = (mt & 7) * 128;
  const float* gA = X + (size_t)bidx * (5632ull * 1024) + (size_t)(kh * 16 + kq * 8) * 1024
                      + p0 + m0;
  int aoff = m0 * 40 + kh * 16 + kq * 8;

  int offA[4], offB[4];
#pragma unroll
  for (int f = 0; f < 4; ++f) {
    int m = wm * 64 + f * 16 + (l & 15);
    offA[f] = m * 40 + (l >> 4) * 8;
    int n = wn * 64 + f * 16 + (l & 15);
    int g = l >> 4;
    offB[f] = (n * 4 + (g ^ ((n >> 1) & 3))) * 8;
  }

  f32x4 acc[4][4] = {};

  auto loadA = [&](float2* va) {
#pragma unroll
    for (int ii = 0; ii < 8; ++ii) va[ii] = *(const float2*)(gA + (size_t)ii * 1024);
  };
  auto stage = [&](const float2* va, s16x8 r0, s16x8 r1, u16* bA, u16* bB) {
    union { u16 u[16]; s16x8 v[2]; } cv;
#pragma unroll
    for (int ii = 0; ii < 8; ++ii) {
      cv.u[ii] = cvt_bf(va[ii].x);
      cv.u[8 + ii] = cvt_bf(va[ii].y);
    }
    *(s16x8*)(bA + aoff) = cv.v[0];
    *(s16x8*)(bA + aoff + 40) = cv.v[1];
    *(s16x8*)(bB + wo0) = r0;
    *(s16x8*)(bB + wo1) = r1;
  };
  auto compute = [&](const u16* bA, const u16* bB) {
    s16x8 af[4], bfr[4];
#pragma unroll
    for (int f = 0; f < 4; ++f) {
      af[f] = *(const s16x8*)(bA + offA[f]);
      bfr[f] = *(const s16x8*)(bB + offB[f]);
    }
#pragma unroll
    for (int ii = 0; ii < 4; ++ii)
#pragma unroll
      for (int j = 0; j < 4; ++j)
        acc[ii][j] = __builtin_amdgcn_mfma_f32_16x16x32_bf16(af[ii], bfr[j], acc[ii][j], 0, 0, 0);
  };

  float2 vaA[8], vaB[8];
  s16x8 rBa0, rBa1, rBb0, rBb1;

  // prologue: tile0 -> buf0; tile1 -> regs
  loadA(vaA); rBa0 = *(const s16x8*)gB0; rBa1 = *(const s16x8*)gB1;
  stage(vaA, rBa0, rBa1, sA[0], sB[0]);
  gA += 32 * 1024; gB0 += 32; gB1 += 32;
  loadA(vaB); rBb0 = *(const s16x8*)gB0; rBb1 = *(const s16x8*)gB1;

  for (int i = 0; i < NT; i += 2) {
    // sub-iter i: compute buf0(tile i); issue tile i+2 -> setA; stage tile i+1 -> buf1
    wg_barrier_lds();
    if (i + 2 < NT) {
      gA += 32 * 1024; gB0 += 32; gB1 += 32;
      loadA(vaA); rBa0 = *(const s16x8*)gB0; rBa1 = *(const s16x8*)gB1;
    }
    compute(sA[0], sB[0]);
    stage(vaB, rBb0, rBb1, sA[1], sB[1]);
    // sub-iter i+1: compute buf1(tile i+1); issue tile i+3 -> setB; stage tile i+2 -> buf0
    wg_barrier_lds();
    if (i + 3 < NT) {
      gA += 32 * 1024; gB0 += 32; gB1 += 32;
      loadA(vaB); rBb0 = *(const s16x8*)gB0; rBb1 = *(const s16x8*)gB1;
    }
    compute(sA[1], sB[1]);
    if (i + 2 < NT) stage(vaA, rBa0, rBa1, sA[0], sB[0]);
  }

  int mb = mt * 128 + wm * 64;
  int nbase = nt * 128 + wn * 64;
#pragma unroll
  for (int j = 0; j < 4; ++j) {
    int n_g = nbase + j * 16 + (l & 15);
    float s = bnS[n_g], tt = bnT[n_g];
#pragma unroll
    for (int i = 0; i < 4; ++i)
#pragma unroll
      for (int r = 0; r < 4; ++r) {
        int m_g = mb + i * 16 + (l >> 4) * 4 + r;
        float v = fmaxf(acc[i][j][r] * s + tt, 0.f);
        H[(size_t)m_g * 512 + n_g] = f2bf(v);
      }
  }
}

// ---------------- GEMM2: 128x128 tile, BK=32, 4 waves; epilogue acc + b2 -> f32
__global__ __launch_bounds__(256, 2) void k_gemm2(
    const u16* __restrict__ A, const u16* __restrict__ B,
    const float* __restrict__ b2, float* __restrict__ C) {
  const int K = 512;
  __shared__ __align__(16) u16 sA[4096];
  __shared__ __align__(16) u16 sB[4096];
  int nb = gridDim.x;
  int id = blockIdx.x;
  int li = (id & 7) * (nb >> 3) + (id >> 3);
  int nt = li % 3;
  int mt = li / 3;
  int t = threadIdx.x;
  int l = t & 63, w = t >> 6;
  int wm = w >> 1, wn = w & 1;

  auto swz = [](int u) { int m = u >> 2, g = u & 3; return (m * 4 + (g ^ ((m >> 1) & 3))) * 8; };
  int wo0 = swz(t), wo1 = swz(t + 256);

  const u16* gA0 = A + (size_t)(mt * 128 + (t >> 2)) * K + (t & 3) * 8;
  const u16* gA1 = gA0 + (size_t)64 * K;
  const u16* gB0 = B + (size_t)(nt * 128 + (t >> 2)) * K + (t & 3) * 8;
  const u16* gB1 = gB0 + (size_t)64 * K;

  int offA[4], offB[4];
#pragma unroll
  for (int f = 0; f < 4; ++f) {
    int g = l >> 4;
    int m = wm * 64 + f * 16 + (l & 15);
    offA[f] = (m * 4 + (g ^ ((m >> 1) & 3))) * 8;
    int n = wn * 64 + f * 16 + (l & 15);
    offB[f] = (n * 4 + (g ^ ((n >> 1) & 3))) * 8;
  }

  f32x4 acc[4][4] = {};

  s16x8 rA0 = *(const s16x8*)gA0;
  s16x8 rA1 = *(const s16x8*)gA1;
  s16x8 rB0 = *(const s16x8*)gB0;
  s16x8 rB1 = *(const s16x8*)gB1;

  for (int k0 = 0; k0 < K; k0 += 32) {
    *(s16x8*)(sA + wo0) = rA0;
    *(s16x8*)(sA + wo1) = rA1;
    *(s16x8*)(sB + wo0) = rB0;
    *(s16x8*)(sB + wo1) = rB1;
    wg_barrier_lds();
    if (k0 + 32 < K) {
      gA0 += 32; gA1 += 32; gB0 += 32; gB1 += 32;
      rA0 = *(const s16x8*)gA0;
      rA1 = *(const s16x8*)gA1;
      rB0 = *(const s16x8*)gB0;
      rB1 = *(const s16x8*)gB1;
    }
    s16x8 af[4], bf[4];
#pragma unroll
    for (int f = 0; f < 4; ++f) {
      af[f] = *(const s16x8*)(sA + offA[f]);
      bf[f] = *(const s16x8*)(sB + offB[f]);
    }
#pragma unroll
    for (int i = 0; i < 4; ++i)
#pragma unroll
      for (int j = 0; j < 4; ++j)
        acc[i][j] = __builtin_amdgcn_mfma_f32_16x16x32_bf16(af[i], bf[j], acc[i][j], 0, 0, 0);
    wg_barrier_lds();
  }

  int mb = mt * 128 + wm * 64;
  int nbase = nt * 128 + wn * 64;
#pragma unroll
  for (int j = 0; j < 4; ++j) {
    int n_g = nbase + j * 16 + (l & 15);
    float bias = b2[n_g];
#pragma unroll
    for (int i = 0; i < 4; ++i)
#pragma unroll
      for (int r = 0; r < 4; ++r) {
        int m_g = mb + i * 16 + (l >> 4) * 4 + r;
        C[(size_t)m_g * 384 + n_g] = acc[i][j][r] + bias;
      }
  }
}

// ---------------- K4: fused DUC + softmax + bilinear(304->256, align_corners)
__global__ __launch_bounds__(256) void k_out(const float* __restrict__ c2,
                                             const float* __restrict__ border2,
                                             float* __restrict__ out) {
  int b = blockIdx.x >> 8;
  int oy = blockIdx.x & 255;
  int ox = threadIdx.x;
  const float SCL = 303.0f / 255.0f;
  float ys = oy * SCL, xs = ox * SCL;
  int y0 = (int)ys; if (y0 > 303) y0 = 303;
  int x0 = (int)xs; if (x0 > 303) x0 = 303;
  float wy = ys - (float)y0, wx = xs - (float)x0;
  int y1 = y0 + 1; if (y1 > 303) y1 = 303;
  int x1 = x0 + 1; if (x1 > 303) x1 = 303;
  int syA[2] = {y0, y1};
  int sxA[2] = {x0, x1};
  float wyA[2] = {1.f - wy, wy};
  float wxA[2] = {1.f - wx, wx};
  float acc[6] = {0.f, 0.f, 0.f, 0.f, 0.f, 0.f};
#pragma unroll
  for (int cy = 0; cy < 2; ++cy) {
#pragma unroll
    for (int cx = 0; cx < 2; ++cx) {
      float wgt = wyA[cy] * wxA[cx];
      int sy = syA[cy], sx = sxA[cx];
      if (sy >= 256 || sx >= 256) {
        float p = wgt * (1.f / 6.f);
#pragma unroll
        for (int c = 0; c < 6; ++c) acc[c] += p;
      } else {
        int i = sy >> 3, j = sx >> 3;
        int sub = ((sy & 7) << 3) | (sx & 7);
        const float* src;
        if (i == 0 || j == 0)
          src = border2 + sub;
        else
          src = c2 + (size_t)((b << 10) + ((i - 1) << 5) + (j - 1)) * 384 + sub;
        float l0 = src[0],   l1 = src[64],  l2 = src[128];
        float l3 = src[192], l4 = src[256], l5 = src[320];
        float mx = fmaxf(fmaxf(fmaxf(l0, l1), fmaxf(l2, l3)), fmaxf(l4, l5));
        float e0 = __expf(l0 - mx), e1 = __expf(l1 - mx), e2 = __expf(l2 - mx);
        float e3 = __expf(l3 - mx), e4 = __expf(l4 - mx), e5 = __expf(l5 - mx);
        float ssum = e0 + e1 + e2 + e3 + e4 + e5;
        float r = wgt / ssum;
        acc[0] += e0 * r; acc[1] += e1 * r; acc[2] += e2 * r;
        acc[3] += e3 * r; acc[4] += e4 * r; acc[5] += e5 * r;
      }
    }
  }
  size_t base = ((size_t)b * 6) << 16;
  int pix = (oy << 8) | ox;
#pragma unroll
  for (int c = 0; c < 6; ++c) out[base + ((size_t)c << 16) + pix] = acc[c];
}

extern "C" void kernel_launch(void* const* d_in, const int* in_sizes, int n_in,
                              void* d_out, int out_size, void* d_ws, size_t ws_size,
                              hipStream_t stream) {
  const float* x     = (const float*)d_in[0];
  const float* w1    = (const float*)d_in[1];
  const float* gamma = (const float*)d_in[2];
  const float* beta  = (const float*)d_in[3];
  const float* mean  = (const float*)d_in[4];
  const float* var   = (const float*)d_in[5];
  const float* w2    = (const float*)d_in[6];
  const float* b2    = (const float*)d_in[7];
  float* out = (float*)d_out;

  char* ws = (char*)d_ws;
  size_t off = 0;
  auto alloc = [&](size_t bytes) -> char* {
    char* p = ws + off;
    off = (off + bytes + 255) & ~(size_t)255;
    return p;
  };
  u16*   w1bf    = (u16*)alloc(512ull * 5632 * 2);
  u16*   w2bf    = (u16*)alloc(384ull * 512 * 2);
  float* bnS     = (float*)alloc(512 * 4);
  float* bnT     = (float*)alloc(512 * 4);
  float* border2 = (float*)alloc(384 * 4);
  u16*   h       = (u16*)alloc(16384ull * 512 * 2);
  float* c2      = (float*)alloc(16384ull * 384 * 4);
  (void)ws_size;

  k_params<<<dim3(1), dim3(512), 0, stream>>>(gamma, beta, mean, var, bnS, bnT);
  k_convert<<<dim3(2816), dim3(256), 0, stream>>>(w1, w1bf, 512 * 5632 / 4);
  k_convert<<<dim3(192), dim3(256), 0, stream>>>(w2, w2bf, 384 * 512 / 4);
  k_border2<<<dim3(384), dim3(64), 0, stream>>>(w2, b2, bnT, border2);

  k_gemm1<<<dim3(512), dim3(256), 0, stream>>>(x, w1bf, bnS, bnT, h);
  k_gemm2<<<dim3(128 * 3), dim3(256), 0, stream>>>(h, w2bf, b2, c2);
  k_out<<<dim3(16 * 256), dim3(256), 0, stream>>>(c2, border2, out);
}